// Round 4
// baseline (41.988 us; speedup 1.0000x reference)
//
#include <hip/hip_runtime.h>

#define IMG_H 720
#define IMG_W 1280
#define IMG_N 2

#define TX 64          // output tile width
#define TY 16          // output tile height
#define NBX (IMG_W / TX)   // 20
#define NBY (IMG_H / TY)   // 45
#define LW 72          // LDS row stride (70 used)
#define LH (TY + 6)    // 22

// -50 * log2(e): color term in exp2 domain
#define C2 (-72.13475204444817f)
// 1/(50*ln2): spatial scale in exp2 domain (exp(-r2/50) = exp2(-r2*S2))
#define S2SCALE (0.028853900817779268f)

#if defined(__has_builtin)
#if __has_builtin(__builtin_amdgcn_rcpf)
#define RCP(x) __builtin_amdgcn_rcpf(x)
#else
#define RCP(x) (1.0f / (x))
#endif
#else
#define RCP(x) (1.0f / (x))
#endif

// Pure-VALU exp2: n = floor(e), f = e-n, cubic for 2^f on [0,1)
// (interpolates f=0,1/3,2/3,1; rel err <= 2.3e-4), then ldexp.
// 7 full-rate VALU ops -> no v_exp_f32 (hypothesis: trans pipe is the
// bottleneck at ~32cy/wave64 on gfx950).
__device__ __forceinline__ float fast_exp2(float e) {
    float nf = floorf(e);             // v_floor_f32
    float f = e - nf;                 // v_sub_f32
    int n = (int)nf;                  // v_cvt_i32_f32
    float p = fmaf(f, 0.07902f, 0.2249955f);   // v_fma
    p = fmaf(f, p, 0.6959845f);                // v_fma
    p = fmaf(f, p, 1.0f);                      // v_fma
    return ldexpf(p, n);                       // v_ldexp_f32
}

__global__ __launch_bounds__(256) void bilateral_tile(
    const float* __restrict__ I, float* __restrict__ O) {
    int b = blockIdx.x;
    int bx = b % NBX;
    int by = (b / NBX) % NBY;
    int n = b / (NBX * NBY);
    int tx0 = bx * TX, ty0 = by * TY;

    __shared__ float S[LH][LW];
    const float* img = I + (size_t)n * IMG_H * IMG_W;
    int tid = threadIdx.x;

    // Stage (TY+6) x 70 window (zero-padded at image borders) into LDS.
#pragma unroll
    for (int i = 0; i < 7; ++i) {
        int idx = tid + i * 256;
        if (idx < LH * LW) {
            int r = idx / LW, col = idx % LW;
            int gy = ty0 - 3 + r, gx = tx0 - 3 + col;
            float v = 0.0f;
            if (col < 70 && gy >= 0 && gy < IMG_H && gx >= 0 && gx < IMG_W)
                v = img[gy * IMG_W + gx];
            S[r][col] = v;
        }
    }
    __syncthreads();

    // Each thread: 4 consecutive output pixels in x.
    int px = tid & 15;        // quad index in tile row: 0..15
    int py = tid >> 4;        // tile row: 0..15
    int x0 = px * 4;

    float c2v = C2;

    float c[4];
#pragma unroll
    for (int p = 0; p < 4; ++p) c[p] = S[py + 3][x0 + 3 + p];

    float acc_w[4] = {0.f, 0.f, 0.f, 0.f};
    float acc_iw[4] = {0.f, 0.f, 0.f, 0.f};

#pragma unroll
    for (int r = 0; r < 7; ++r) {
        const float* row = &S[py + r][x0];
        float4 a = *(const float4*)(row);
        float4 bb = *(const float4*)(row + 4);
        float4 d4 = *(const float4*)(row + 8);
        float f[12] = {a.x, a.y, a.z, a.w, bb.x, bb.y, bb.z, bb.w,
                       d4.x, d4.y, d4.z, d4.w};
        const int ry2 = (r - 3) * (r - 3);
#pragma unroll
        for (int p = 0; p < 4; ++p) {
#pragma unroll
            for (int dx = 0; dx < 7; ++dx) {
                if (r == 3 && dx == 3) {
                    // center tap: w = exp2(0) = 1 exactly
                    acc_w[p] += 1.0f;
                    acc_iw[p] += c[p];
                    continue;
                }
                float v = f[p + dx];
                const float s2 = -(float)(ry2 + (dx - 3) * (dx - 3)) * S2SCALE;
                float dd = v - c[p];
                float e = fmaf(dd * dd, c2v, s2);
                float w = fast_exp2(e);
                acc_w[p] += w;
                acc_iw[p] = fmaf(w, v, acc_iw[p]);
            }
        }
    }

    float* out = O + ((size_t)n * IMG_H + (ty0 + py)) * IMG_W + tx0 + x0;
    float4 rr;
    rr.x = acc_iw[0] * RCP(acc_w[0]);
    rr.y = acc_iw[1] * RCP(acc_w[1]);
    rr.z = acc_iw[2] * RCP(acc_w[2]);
    rr.w = acc_iw[3] * RCP(acc_w[3]);
    *(float4*)out = rr;
}

extern "C" void kernel_launch(void* const* d_in, const int* in_sizes, int n_in,
                              void* d_out, int out_size, void* d_ws, size_t ws_size,
                              hipStream_t stream) {
    const float* I = (const float*)d_in[0];
    float* O = (float*)d_out;
    const int blocks = IMG_N * NBX * NBY;  // 1800
    bilateral_tile<<<blocks, 256, 0, stream>>>(I, O);
}

// Round 5
// 28.242 us; speedup vs baseline: 1.4867x; 1.4867x over previous
//
#include <hip/hip_runtime.h>

#define IMG_H 720
#define IMG_W 1280
#define IMG_N 2

#define TX 64          // output tile width
#define TY 16          // output tile height
#define NBX (IMG_W / TX)   // 20
#define NBY (IMG_H / TY)   // 45
#define LW 76          // LDS row stride in words: 12*py+4*px mod 32 tiles banks
#define LH (TY + 6)    // 22

// -50 * log2(e): color term in exp2 domain
#define C2 (-72.13475204444817f)
// 1/(50*ln2): spatial scale in exp2 domain (exp(-r2/50) = exp2(-r2*S2))
#define S2SCALE (0.028853900817779268f)

#if defined(__has_builtin)
#if __has_builtin(__builtin_amdgcn_exp2f)
#define EXP2(x) __builtin_amdgcn_exp2f(x)
#else
#define EXP2(x) exp2f(x)
#endif
#if __has_builtin(__builtin_amdgcn_rcpf)
#define RCP(x) __builtin_amdgcn_rcpf(x)
#else
#define RCP(x) (1.0f / (x))
#endif
#else
#define EXP2(x) exp2f(x)
#define RCP(x) (1.0f / (x))
#endif

// 8 waves/EU requested -> register allocator capped at 64 VGPR -> 8 waves/SIMD
// (m69: occupancy halves at the 64/128 VGPR thresholds; 104 VGPR was 4 waves).
__global__ __launch_bounds__(256, 8) void bilateral_tile(
    const float* __restrict__ I, float* __restrict__ O) {
    int b = blockIdx.x;
    int bx = b % NBX;
    int by = (b / NBX) % NBY;
    int n = b / (NBX * NBY);
    int tx0 = bx * TX, ty0 = by * TY;

    __shared__ float S[LH][LW];
    const float* img = I + (size_t)n * IMG_H * IMG_W;
    int tid = threadIdx.x;

    // Stage (TY+6) x 70 window (zero-padded at image borders) into LDS.
    // Linear word index -> conflict-free b32 writes.
#pragma unroll
    for (int i = 0; i < 7; ++i) {
        int idx = tid + i * 256;
        if (idx < LH * LW) {
            int r = idx / LW, col = idx % LW;
            int gy = ty0 - 3 + r, gx = tx0 - 3 + col;
            float v = 0.0f;
            if (col < 70 && gy >= 0 && gy < IMG_H && gx >= 0 && gx < IMG_W)
                v = img[gy * IMG_W + gx];
            S[r][col] = v;
        }
    }
    __syncthreads();

    // Each thread: 4 consecutive output pixels in x.
    int px = tid & 15;        // quad index in tile row: 0..15
    int py = tid >> 4;        // tile row: 0..15
    int x0 = px * 4;

    float c2v = C2;

    float c[4];
#pragma unroll
    for (int p = 0; p < 4; ++p) c[p] = S[py + 3][x0 + 3 + p];

    float acc_w[4] = {0.f, 0.f, 0.f, 0.f};
    float acc_iw[4] = {0.f, 0.f, 0.f, 0.f};

#pragma unroll
    for (int r = 0; r < 7; ++r) {
        const float* row = &S[py + r][x0];
        float4 a = *(const float4*)(row);
        float4 bb = *(const float4*)(row + 4);
        float4 d4 = *(const float4*)(row + 8);
        float f[12] = {a.x, a.y, a.z, a.w, bb.x, bb.y, bb.z, bb.w,
                       d4.x, d4.y, d4.z, d4.w};
        const int ry2 = (r - 3) * (r - 3);
#pragma unroll
        for (int p = 0; p < 4; ++p) {
#pragma unroll
            for (int dx = 0; dx < 7; ++dx) {
                float v = f[p + dx];
                const float s2 = -(float)(ry2 + (dx - 3) * (dx - 3)) * S2SCALE;
                float dd = v - c[p];
                float e = fmaf(dd * dd, c2v, s2);
                float w = EXP2(e);
                acc_w[p] += w;
                acc_iw[p] = fmaf(w, v, acc_iw[p]);
            }
        }
    }

    float* out = O + ((size_t)n * IMG_H + (ty0 + py)) * IMG_W + tx0 + x0;
    float4 rr;
    rr.x = acc_iw[0] * RCP(acc_w[0]);
    rr.y = acc_iw[1] * RCP(acc_w[1]);
    rr.z = acc_iw[2] * RCP(acc_w[2]);
    rr.w = acc_iw[3] * RCP(acc_w[3]);
    *(float4*)out = rr;
}

extern "C" void kernel_launch(void* const* d_in, const int* in_sizes, int n_in,
                              void* d_out, int out_size, void* d_ws, size_t ws_size,
                              hipStream_t stream) {
    const float* I = (const float*)d_in[0];
    float* O = (float*)d_out;
    const int blocks = IMG_N * NBX * NBY;  // 1800
    bilateral_tile<<<blocks, 256, 0, stream>>>(I, O);
}

// Round 6
// 23.906 us; speedup vs baseline: 1.7564x; 1.1813x over previous
//
#include <hip/hip_runtime.h>

#define IMG_H 720
#define IMG_W 1280
#define IMG_N 2

#define TX 64          // output tile width
#define TY 16          // output tile height
#define NBX (IMG_W / TX)   // 20
#define NBY (IMG_H / TY)   // 45
#define LW 72          // LDS row stride in words (2-way b128 conflict = free, m136)
#define LH (TY + 6)    // 22
#define NCHUNK (LH * (LW / 4))  // 396 float4 chunks per tile

// k = sqrt(50 * log2(e)); exponent: -(k*v - k*c)^2 - (r2)*S2SCALE
#define KSCALE 8.493218148592486f
#define INVK   0.11774100235949044f
#define S2SCALE 0.028853900817779268f  // 1/(50*ln2)

#if defined(__has_builtin)
#if __has_builtin(__builtin_amdgcn_exp2f)
#define EXP2(x) __builtin_amdgcn_exp2f(x)
#else
#define EXP2(x) exp2f(x)
#endif
#if __has_builtin(__builtin_amdgcn_rcpf)
#define RCP(x) __builtin_amdgcn_rcpf(x)
#else
#define RCP(x) (1.0f / (x))
#endif
#else
#define EXP2(x) exp2f(x)
#define RCP(x) (1.0f / (x))
#endif

// Per-row taps. fk values are k-pre-scaled; acc_iw accumulates in k-domain.
__device__ __forceinline__ void do_row(const float* __restrict__ rowptr,
                                       const float ck[4], float acc_w[4],
                                       float acc_iw[4], const int ry2) {
    float4 a = *(const float4*)(rowptr);
    float4 bb = *(const float4*)(rowptr + 4);
    float4 d4 = *(const float4*)(rowptr + 8);
    float fk[12] = {a.x, a.y, a.z, a.w, bb.x, bb.y, bb.z, bb.w,
                    d4.x, d4.y, d4.z, d4.w};
#pragma unroll
    for (int p = 0; p < 4; ++p) {
#pragma unroll
        for (int dx = 0; dx < 7; ++dx) {
            const float s2 = -(float)(ry2 + (dx - 3) * (dx - 3)) * S2SCALE;
            float v = fk[p + dx];
            float dd = v - ck[p];
            float e = fmaf(-dd, dd, s2);   // v_fma with neg modifier: 1 inst
            float w = EXP2(e);
            acc_w[p] += w;
            acc_iw[p] = fmaf(w, v, acc_iw[p]);
        }
    }
}

__global__ __launch_bounds__(256) void bilateral_tile(
    const float* __restrict__ I, float* __restrict__ O) {
    int b = blockIdx.x;
    int bx = b % NBX;
    int by = (b / NBX) % NBY;
    int n = b / (NBX * NBY);
    int tx0 = bx * TX, ty0 = by * TY;

    __shared__ float S[LH][LW];
    const float* img = I + (size_t)n * IMG_H * IMG_W;
    int tid = threadIdx.x;

    // ---- stage (k-pre-scaled) ----
    bool interior = (bx >= 1) && (bx <= NBX - 2) && (by >= 1) && (by <= NBY - 2);
    if (interior) {
        // float4 loads (dword-aligned ok) + b128 LDS writes; no bounds checks.
#pragma unroll
        for (int i = 0; i < 2; ++i) {
            int id = tid + i * 256;
            if (id < NCHUNK) {
                int r = id / (LW / 4);
                int q = id % (LW / 4);
                int gy = ty0 - 3 + r, gx = tx0 - 3 + q * 4;
                float4 v = *(const float4*)(img + gy * IMG_W + gx);
                v.x *= KSCALE; v.y *= KSCALE; v.z *= KSCALE; v.w *= KSCALE;
                *(float4*)(&S[r][q * 4]) = v;
            }
        }
    } else {
        // border tile: scalar loads with zero-pad semantics
#pragma unroll
        for (int i = 0; i < 7; ++i) {
            int idx = tid + i * 256;
            if (idx < LH * LW) {
                int r = idx / LW, col = idx % LW;
                int gy = ty0 - 3 + r, gx = tx0 - 3 + col;
                float v = 0.0f;
                if (col < 70 && gy >= 0 && gy < IMG_H && gx >= 0 && gx < IMG_W)
                    v = img[gy * IMG_W + gx];
                S[r][col] = v * KSCALE;
            }
        }
    }
    __syncthreads();

    // ---- compute: 4 consecutive output pixels per thread ----
    int px = tid & 15;
    int py = tid >> 4;
    int x0 = px * 4;

    float acc_w[4] = {0.f, 0.f, 0.f, 0.f};
    float acc_iw[4] = {0.f, 0.f, 0.f, 0.f};
    float ck[4];

    // Row 3 first: center values come from this row's registers (no extra
    // LDS reads). Row order doesn't change the sum beyond fp reassociation.
    {
        const float* row = &S[py + 3][x0];
        float4 a = *(const float4*)(row);
        float4 bb = *(const float4*)(row + 4);
        float4 d4 = *(const float4*)(row + 8);
        float fk[12] = {a.x, a.y, a.z, a.w, bb.x, bb.y, bb.z, bb.w,
                        d4.x, d4.y, d4.z, d4.w};
#pragma unroll
        for (int p = 0; p < 4; ++p) ck[p] = fk[3 + p];
#pragma unroll
        for (int p = 0; p < 4; ++p) {
#pragma unroll
            for (int dx = 0; dx < 7; ++dx) {
                const float s2 = -(float)((dx - 3) * (dx - 3)) * S2SCALE;
                float v = fk[p + dx];
                float dd = v - ck[p];
                float e = fmaf(-dd, dd, s2);
                float w = EXP2(e);
                acc_w[p] += w;
                acc_iw[p] = fmaf(w, v, acc_iw[p]);
            }
        }
    }
    do_row(&S[py + 0][x0], ck, acc_w, acc_iw, 9);
    do_row(&S[py + 1][x0], ck, acc_w, acc_iw, 4);
    do_row(&S[py + 2][x0], ck, acc_w, acc_iw, 1);
    do_row(&S[py + 4][x0], ck, acc_w, acc_iw, 1);
    do_row(&S[py + 5][x0], ck, acc_w, acc_iw, 4);
    do_row(&S[py + 6][x0], ck, acc_w, acc_iw, 9);

    float* out = O + ((size_t)n * IMG_H + (ty0 + py)) * IMG_W + tx0 + x0;
    float4 rr;
    rr.x = acc_iw[0] * RCP(acc_w[0]) * INVK;
    rr.y = acc_iw[1] * RCP(acc_w[1]) * INVK;
    rr.z = acc_iw[2] * RCP(acc_w[2]) * INVK;
    rr.w = acc_iw[3] * RCP(acc_w[3]) * INVK;
    *(float4*)out = rr;
}

extern "C" void kernel_launch(void* const* d_in, const int* in_sizes, int n_in,
                              void* d_out, int out_size, void* d_ws, size_t ws_size,
                              hipStream_t stream) {
    const float* I = (const float*)d_in[0];
    float* O = (float*)d_out;
    const int blocks = IMG_N * NBX * NBY;  // 1800
    bilateral_tile<<<blocks, 256, 0, stream>>>(I, O);
}

// Round 7
// 23.786 us; speedup vs baseline: 1.7652x; 1.0051x over previous
//
#include <hip/hip_runtime.h>

#define IMG_H 720
#define IMG_W 1280
#define IMG_N 2

#define TX 64          // output tile width
#define TY 16          // output tile height
#define NBX (IMG_W / TX)   // 20
#define NBY (IMG_H / TY)   // 45
#define LW 72          // LDS row stride in words (2-way b128 conflict = free, m136)
#define LH (TY + 6)    // 22
#define NCHUNK (LH * (LW / 4))  // 396 float4 chunks per tile

// k = sqrt(50 * log2(e)); exponent: -(k*v - k*c)^2 - (r2)*S2SCALE
#define KSCALE 8.493218148592486f
#define INVK   0.11774100235949044f
#define S2SCALE 0.028853900817779268f  // 1/(50*ln2)

#if defined(__has_builtin)
#if __has_builtin(__builtin_amdgcn_exp2f)
#define EXP2(x) __builtin_amdgcn_exp2f(x)
#else
#define EXP2(x) exp2f(x)
#endif
#if __has_builtin(__builtin_amdgcn_rcpf)
#define RCP(x) __builtin_amdgcn_rcpf(x)
#else
#define RCP(x) (1.0f / (x))
#endif
#else
#define EXP2(x) exp2f(x)
#define RCP(x) (1.0f / (x))
#endif

// Per-row taps. fk values are k-pre-scaled; acc_iw accumulates in k-domain.
__device__ __forceinline__ void do_row(const float* __restrict__ rowptr,
                                       const float ck[4], float acc_w[4],
                                       float acc_iw[4], const int ry2) {
    float4 a = *(const float4*)(rowptr);
    float4 bb = *(const float4*)(rowptr + 4);
    float4 d4 = *(const float4*)(rowptr + 8);
    float fk[12] = {a.x, a.y, a.z, a.w, bb.x, bb.y, bb.z, bb.w,
                    d4.x, d4.y, d4.z, d4.w};
#pragma unroll
    for (int p = 0; p < 4; ++p) {
#pragma unroll
        for (int dx = 0; dx < 7; ++dx) {
            const float s2 = -(float)(ry2 + (dx - 3) * (dx - 3)) * S2SCALE;
            float v = fk[p + dx];
            float dd = v - ck[p];
            float e = fmaf(-dd, dd, s2);   // v_fma with neg modifier: 1 inst
            float w = EXP2(e);
            acc_w[p] += w;
            acc_iw[p] = fmaf(w, v, acc_iw[p]);
        }
    }
}

// Single change vs round 5: request 8 waves/EU -> VGPR capped at 64 ->
// 8 waves/SIMD, 8 blocks/CU (all 1800 blocks co-resident, no tail).
__global__ __launch_bounds__(256, 8) void bilateral_tile(
    const float* __restrict__ I, float* __restrict__ O) {
    int b = blockIdx.x;
    int bx = b % NBX;
    int by = (b / NBX) % NBY;
    int n = b / (NBX * NBY);
    int tx0 = bx * TX, ty0 = by * TY;

    __shared__ float S[LH][LW];
    const float* img = I + (size_t)n * IMG_H * IMG_W;
    int tid = threadIdx.x;

    // ---- stage (k-pre-scaled) ----
    bool interior = (bx >= 1) && (bx <= NBX - 2) && (by >= 1) && (by <= NBY - 2);
    if (interior) {
        // float4 loads (dword-aligned ok) + b128 LDS writes; no bounds checks.
#pragma unroll
        for (int i = 0; i < 2; ++i) {
            int id = tid + i * 256;
            if (id < NCHUNK) {
                int r = id / (LW / 4);
                int q = id % (LW / 4);
                int gy = ty0 - 3 + r, gx = tx0 - 3 + q * 4;
                float4 v = *(const float4*)(img + gy * IMG_W + gx);
                v.x *= KSCALE; v.y *= KSCALE; v.z *= KSCALE; v.w *= KSCALE;
                *(float4*)(&S[r][q * 4]) = v;
            }
        }
    } else {
        // border tile: scalar loads with zero-pad semantics
#pragma unroll
        for (int i = 0; i < 7; ++i) {
            int idx = tid + i * 256;
            if (idx < LH * LW) {
                int r = idx / LW, col = idx % LW;
                int gy = ty0 - 3 + r, gx = tx0 - 3 + col;
                float v = 0.0f;
                if (col < 70 && gy >= 0 && gy < IMG_H && gx >= 0 && gx < IMG_W)
                    v = img[gy * IMG_W + gx];
                S[r][col] = v * KSCALE;
            }
        }
    }
    __syncthreads();

    // ---- compute: 4 consecutive output pixels per thread ----
    int px = tid & 15;
    int py = tid >> 4;
    int x0 = px * 4;

    float acc_w[4] = {0.f, 0.f, 0.f, 0.f};
    float acc_iw[4] = {0.f, 0.f, 0.f, 0.f};
    float ck[4];

    // Row 3 first: center values come from this row's registers (no extra
    // LDS reads). Row order doesn't change the sum beyond fp reassociation.
    {
        const float* row = &S[py + 3][x0];
        float4 a = *(const float4*)(row);
        float4 bb = *(const float4*)(row + 4);
        float4 d4 = *(const float4*)(row + 8);
        float fk[12] = {a.x, a.y, a.z, a.w, bb.x, bb.y, bb.z, bb.w,
                        d4.x, d4.y, d4.z, d4.w};
#pragma unroll
        for (int p = 0; p < 4; ++p) ck[p] = fk[3 + p];
#pragma unroll
        for (int p = 0; p < 4; ++p) {
#pragma unroll
            for (int dx = 0; dx < 7; ++dx) {
                const float s2 = -(float)((dx - 3) * (dx - 3)) * S2SCALE;
                float v = fk[p + dx];
                float dd = v - ck[p];
                float e = fmaf(-dd, dd, s2);
                float w = EXP2(e);
                acc_w[p] += w;
                acc_iw[p] = fmaf(w, v, acc_iw[p]);
            }
        }
    }
    do_row(&S[py + 0][x0], ck, acc_w, acc_iw, 9);
    do_row(&S[py + 1][x0], ck, acc_w, acc_iw, 4);
    do_row(&S[py + 2][x0], ck, acc_w, acc_iw, 1);
    do_row(&S[py + 4][x0], ck, acc_w, acc_iw, 1);
    do_row(&S[py + 5][x0], ck, acc_w, acc_iw, 4);
    do_row(&S[py + 6][x0], ck, acc_w, acc_iw, 9);

    float* out = O + ((size_t)n * IMG_H + (ty0 + py)) * IMG_W + tx0 + x0;
    float4 rr;
    rr.x = acc_iw[0] * RCP(acc_w[0]) * INVK;
    rr.y = acc_iw[1] * RCP(acc_w[1]) * INVK;
    rr.z = acc_iw[2] * RCP(acc_w[2]) * INVK;
    rr.w = acc_iw[3] * RCP(acc_w[3]) * INVK;
    *(float4*)out = rr;
}

extern "C" void kernel_launch(void* const* d_in, const int* in_sizes, int n_in,
                              void* d_out, int out_size, void* d_ws, size_t ws_size,
                              hipStream_t stream) {
    const float* I = (const float*)d_in[0];
    float* O = (float*)d_out;
    const int blocks = IMG_N * NBX * NBY;  // 1800
    bilateral_tile<<<blocks, 256, 0, stream>>>(I, O);
}